// Round 3
// baseline (620.573 us; speedup 1.0000x reference)
//
#include <hip/hip_runtime.h>
#include <stdint.h>

typedef __attribute__((ext_vector_type(4))) float f32x4;
typedef __attribute__((ext_vector_type(8))) short short8;

#define MFMA16(a, b, c) __builtin_amdgcn_mfma_f32_16x16x32_bf16((a), (b), (c), 0, 0, 0)

__device__ __forceinline__ unsigned short f2bf(float f) {
  unsigned int x = __float_as_uint(f);
  return (unsigned short)((x + 0x7fffu + ((x >> 16) & 1u)) >> 16);
}

__device__ __forceinline__ void load8cv(const float* __restrict__ s, void* d) {
  const f32x4* p = (const f32x4*)s;
  f32x4 a = p[0], b = p[1];
  short8 t;
  t[0] = (short)f2bf(a[0]); t[1] = (short)f2bf(a[1]);
  t[2] = (short)f2bf(a[2]); t[3] = (short)f2bf(a[3]);
  t[4] = (short)f2bf(b[0]); t[5] = (short)f2bf(b[1]);
  t[6] = (short)f2bf(b[2]); t[7] = (short)f2bf(b[3]);
  *(short8*)d = t;
}
__device__ __forceinline__ void load8cv(const unsigned short* __restrict__ s, void* d) {
  *(short8*)d = *(const short8*)s;
}

__device__ __forceinline__ void storec(float* p, float v) { *p = v; }
__device__ __forceinline__ void storec(unsigned short* p, float v) { *p = f2bf(v); }

// ---------------------------------------------------------------------------
// Round-1 GEMM config restored: 128x128 tile, BK=32, 4 waves (2x2), 4x4 frags.
// ---------------------------------------------------------------------------
template <typename TA, typename TOUT>
__global__ __launch_bounds__(256) void gemm_bias(const TA* __restrict__ A,
                                                 const float* __restrict__ Bt,
                                                 const float* __restrict__ bias,
                                                 TOUT* __restrict__ C,
                                                 int M, int N, int K, float oscale) {
  constexpr int AST = 40;
  __shared__ unsigned short As[128 * AST];
  __shared__ unsigned short Bs[128 * AST];
  const int tid = threadIdx.x;
  const int lane = tid & 63;
  const int wv = tid >> 6;
  const int g = lane >> 4, r = lane & 15;
  const int wm = wv >> 1, wn = wv & 1;
  const int m0 = blockIdx.y * 128, n0 = blockIdx.x * 128;

  f32x4 acc[4][4];
#pragma unroll
  for (int m = 0; m < 4; ++m)
#pragma unroll
    for (int n = 0; n < 4; ++n) acc[m][n] = (f32x4){0.f, 0.f, 0.f, 0.f};

  for (int k0 = 0; k0 < K; k0 += 32) {
    __syncthreads();
#pragma unroll
    for (int cc = 0; cc < 2; ++cc) {
      int chunk = tid + cc * 256;
      int row = chunk >> 2;
      int kc = (chunk & 3) * 8;
      load8cv(A + (size_t)(m0 + row) * K + k0 + kc, &As[row * AST + kc]);
      load8cv(Bt + (size_t)(n0 + row) * K + k0 + kc, &Bs[row * AST + kc]);
    }
    __syncthreads();
    short8 af[4], bfr[4];
#pragma unroll
    for (int m = 0; m < 4; ++m)
      af[m] = *(const short8*)&As[(wm * 64 + m * 16 + r) * AST + g * 8];
#pragma unroll
    for (int n = 0; n < 4; ++n)
      bfr[n] = *(const short8*)&Bs[(wn * 64 + n * 16 + r) * AST + g * 8];
#pragma unroll
    for (int m = 0; m < 4; ++m)
#pragma unroll
      for (int n = 0; n < 4; ++n) acc[m][n] = MFMA16(af[m], bfr[n], acc[m][n]);
  }

#pragma unroll
  for (int n = 0; n < 4; ++n) {
    int col = n0 + wn * 64 + n * 16 + r;
    float bv = bias[col];
#pragma unroll
    for (int m = 0; m < 4; ++m) {
#pragma unroll
      for (int i = 0; i < 4; ++i) {
        int rowg = m0 + wm * 64 + m * 16 + 4 * g + i;
        storec(C + (size_t)rowg * N + col, (acc[m][n][i] + bv) * oscale);
      }
    }
  }
}

// ---------------------------------------------------------------------------
// V16[b*2048+s][h*64+d] -> Vt[(b*16+h)*64+d][s]  (bf16)
// ---------------------------------------------------------------------------
__global__ __launch_bounds__(256) void transpose_v(const unsigned short* __restrict__ V,
                                                   unsigned short* __restrict__ Vt) {
  int t = blockIdx.x * 256 + threadIdx.x;
  int d = t & 63;
  int sc = (t >> 6) & 255;
  int bh = t >> 14;
  int b = bh >> 4, h = bh & 15;
  unsigned short vals[8];
#pragma unroll
  for (int j = 0; j < 8; ++j)
    vals[j] = V[(size_t)(b * 2048 + sc * 8 + j) * 1024 + h * 64 + d];
  *(short8*)&Vt[((size_t)bh * 64 + d) * 2048 + sc * 8] = *(short8*)vals;
}

// ---------------------------------------------------------------------------
// Barrier-free fused attention. 4 waves x 16 q-rows; Q pre-scaled by 1/8.
// K and Vt operand fragments are DIRECT 16B global loads (L2-resident,
// 512 KB per (b,h), shared by 32 blocks -> XCD-chunked swizzle for locality).
// LDS = per-wave-private 4KB f32 P tile only (P transpose + coalesced
// dwordx4 attention stores). NO __syncthreads anywhere.
// Pass 1: plain exp-sum (scores bounded, no max needed), reduce once at end.
// Pass 2: recompute scores, P -> LDS -> {attn store, bf16 A-frags}, PV MFMA.
// ---------------------------------------------------------------------------
__global__ __launch_bounds__(256) void attn_fused(const unsigned short* __restrict__ Q,
                                                  const unsigned short* __restrict__ K,
                                                  const unsigned short* __restrict__ Vt,
                                                  float* __restrict__ attn,
                                                  unsigned short* __restrict__ O) {
  __shared__ char pball[4][4096];
  const int tid = threadIdx.x;
  const int lane = tid & 63;
  const int wv = tid >> 6;
  const int g = lane >> 4, r = lane & 15;
  // XCD-chunked bijective swizzle (1024 blocks, 8 XCDs, 128 per XCD):
  // all 32 q-tiles of a (b,h) land on one XCD -> K/V L2-local.
  int nb = (blockIdx.x & 7) * 128 + (blockIdx.x >> 3);
  const int qt = nb & 31, bh = nb >> 5;
  const int h = bh & 15, b = bh >> 4;
  const int qloc = qt * 64 + wv * 16;
  const int qrow0 = b * 2048 + qloc;
  const unsigned short* Kr = K + (size_t)b * 2048 * 1024 + h * 64 + (size_t)r * 1024;
  const unsigned short* Vr = Vt + ((size_t)bh * 64 + r) * 2048;
  float* attn_bh = attn + (size_t)bh * 2048 * 2048;
  char* pbw = pball[wv];

  short8 qf[2];
#pragma unroll
  for (int kk = 0; kk < 2; ++kk)
    qf[kk] = *(const short8*)&Q[(size_t)(qrow0 + r) * 1024 + h * 64 + kk * 32 + g * 8];

  // ---------------- pass 1: row sums of exp (no barriers, no LDS) ----------
  float lrow[4] = {0.f, 0.f, 0.f, 0.f};
  for (int kt = 0; kt < 2048; kt += 64) {
#pragma unroll
    for (int ct = 0; ct < 4; ++ct) {
      const unsigned short* kp = Kr + (size_t)(kt + ct * 16) * 1024 + g * 8;
      f32x4 s = (f32x4){0.f, 0.f, 0.f, 0.f};
      s = MFMA16(qf[0], *(const short8*)kp, s);
      s = MFMA16(qf[1], *(const short8*)(kp + 32), s);
#pragma unroll
      for (int i = 0; i < 4; ++i) lrow[i] += __expf(s[i]);
    }
  }
  float linv[4];
#pragma unroll
  for (int i = 0; i < 4; ++i) {
    float l = lrow[i];
    l += __shfl_xor(l, 1);
    l += __shfl_xor(l, 2);
    l += __shfl_xor(l, 4);
    l += __shfl_xor(l, 8);
    linv[i] = 1.0f / l;
  }

  // ---------------- pass 2: normalized P + coalesced store + PV ------------
  f32x4 oacc[4];
#pragma unroll
  for (int i = 0; i < 4; ++i) oacc[i] = (f32x4){0.f, 0.f, 0.f, 0.f};

  for (int kt = 0; kt < 2048; kt += 64) {
    f32x4 s[4];
#pragma unroll
    for (int ct = 0; ct < 4; ++ct) {
      const unsigned short* kp = Kr + (size_t)(kt + ct * 16) * 1024 + g * 8;
      s[ct] = (f32x4){0.f, 0.f, 0.f, 0.f};
      s[ct] = MFMA16(qf[0], *(const short8*)kp, s[ct]);
      s[ct] = MFMA16(qf[1], *(const short8*)(kp + 32), s[ct]);
    }
    // normalized p -> per-wave swizzled f32 LDS tile [16][64]
#pragma unroll
    for (int ct = 0; ct < 4; ++ct) {
#pragma unroll
      for (int i = 0; i < 4; ++i) {
        float p = __expf(s[ct][i]) * linv[i];
        int prow = 4 * g + i;
        *(float*)(pbw + ((prow * 256 + (ct * 16 + r) * 4) ^ ((prow & 7) << 4))) = p;
      }
    }
    // coalesced attention store: 4 insts x (4 rows x 256B contiguous)
#pragma unroll
    for (int rep = 0; rep < 4; ++rep) {
      int row = rep * 4 + g;
      f32x4 pv4 = *(const f32x4*)(pbw + ((row * 256 + r * 16) ^ ((row & 7) << 4)));
      *(f32x4*)&attn_bh[(size_t)(qloc + row) * 2048 + kt + r * 4] = pv4;
    }
    // PV: O[16q x 64d] += P[16x64] @ V[64x64], V frags direct from Vt
#pragma unroll
    for (int kk2 = 0; kk2 < 2; ++kk2) {
      int cb = kk2 * 128 + g * 32;
      f32x4 pa0 = *(const f32x4*)(pbw + ((r * 256 + cb) ^ ((r & 7) << 4)));
      f32x4 pa1 = *(const f32x4*)(pbw + ((r * 256 + cb + 16) ^ ((r & 7) << 4)));
      short8 pa;
#pragma unroll
      for (int j = 0; j < 4; ++j) {
        pa[j] = (short)f2bf(pa0[j]);
        pa[4 + j] = (short)f2bf(pa1[j]);
      }
#pragma unroll
      for (int ct2 = 0; ct2 < 4; ++ct2) {
        const unsigned short* vp = Vr + (size_t)(ct2 * 16) * 2048 + kt + kk2 * 32 + g * 8;
        oacc[ct2] = MFMA16(pa, *(const short8*)vp, oacc[ct2]);
      }
    }
  }
#pragma unroll
  for (int ct2 = 0; ct2 < 4; ++ct2)
#pragma unroll
    for (int i = 0; i < 4; ++i)
      O[(size_t)(qrow0 + 4 * g + i) * 1024 + h * 64 + ct2 * 16 + r] = f2bf(oacc[ct2][i]);
}

// ---------------------------------------------------------------------------
extern "C" void kernel_launch(void* const* d_in, const int* in_sizes, int n_in,
                              void* d_out, int out_size, void* d_ws, size_t ws_size,
                              hipStream_t stream) {
  const float* q_in = (const float*)d_in[0];
  const float* k_in = (const float*)d_in[1];
  const float* v_in = (const float*)d_in[2];
  const float* wq = (const float*)d_in[3];
  const float* bq = (const float*)d_in[4];
  const float* wk = (const float*)d_in[5];
  const float* bk = (const float*)d_in[6];
  const float* wv = (const float*)d_in[7];
  const float* bv = (const float*)d_in[8];
  const float* wo = (const float*)d_in[9];
  const float* bo = (const float*)d_in[10];

  char* ws = (char*)d_ws;
  const size_t MB8 = 8ull * 1024 * 1024;
  unsigned short* Q16 = (unsigned short*)(ws);
  unsigned short* K16 = (unsigned short*)(ws + MB8);
  unsigned short* V16 = (unsigned short*)(ws + 2 * MB8);
  unsigned short* Vt  = (unsigned short*)(ws + 3 * MB8);
  unsigned short* O16 = (unsigned short*)(ws + 4 * MB8);

  float* out = (float*)d_out;
  float* attn = out + 4194304ull;

  dim3 blk(256);
  dim3 gproj(8, 32);  // N/128 x M/128
  gemm_bias<float, unsigned short><<<gproj, blk, 0, stream>>>(q_in, wq, bq, Q16, 4096, 1024, 1024, 0.125f);
  gemm_bias<float, unsigned short><<<gproj, blk, 0, stream>>>(k_in, wk, bk, K16, 4096, 1024, 1024, 1.0f);
  gemm_bias<float, unsigned short><<<gproj, blk, 0, stream>>>(v_in, wv, bv, V16, 4096, 1024, 1024, 1.0f);
  transpose_v<<<dim3(2048), blk, 0, stream>>>(V16, Vt);
  attn_fused<<<dim3(1024), blk, 0, stream>>>(Q16, K16, Vt, attn, O16);
  gemm_bias<unsigned short, float><<<gproj, blk, 0, stream>>>(O16, wo, bo, out, 4096, 1024, 1024, 1.0f);
}

// Round 4
// 393.292 us; speedup vs baseline: 1.5779x; 1.5779x over previous
//
#include <hip/hip_runtime.h>
#include <stdint.h>

typedef __attribute__((ext_vector_type(4))) float f32x4;
typedef __attribute__((ext_vector_type(8))) short short8;

#define MFMA16(a, b, c) __builtin_amdgcn_mfma_f32_16x16x32_bf16((a), (b), (c), 0, 0, 0)

__device__ __forceinline__ unsigned short f2bf(float f) {
  unsigned int x = __float_as_uint(f);
  return (unsigned short)((x + 0x7fffu + ((x >> 16) & 1u)) >> 16);
}
__device__ __forceinline__ float bf2f(unsigned short u) {
  return __uint_as_float(((unsigned int)u) << 16);
}

__device__ __forceinline__ void gl2lds16(const void* g, void* l) {
  __builtin_amdgcn_global_load_lds((const __attribute__((address_space(1))) void*)g,
                                   (__attribute__((address_space(3))) void*)l, 16, 0, 0);
}

__device__ __forceinline__ void load8cv(const float* __restrict__ s, void* d) {
  const f32x4* p = (const f32x4*)s;
  f32x4 a = p[0], b = p[1];
  short8 t;
  t[0] = (short)f2bf(a[0]); t[1] = (short)f2bf(a[1]);
  t[2] = (short)f2bf(a[2]); t[3] = (short)f2bf(a[3]);
  t[4] = (short)f2bf(b[0]); t[5] = (short)f2bf(b[1]);
  t[6] = (short)f2bf(b[2]); t[7] = (short)f2bf(b[3]);
  *(short8*)d = t;
}

__device__ __forceinline__ void storec(float* p, float v) { *p = v; }
__device__ __forceinline__ void storec(unsigned short* p, float v) { *p = f2bf(v); }

// counted-vmcnt barrier pair: allow 4 prefetch loads to stay in flight
#define BAR_V4 asm volatile("s_waitcnt vmcnt(4)\ns_barrier" ::: "memory")
#define BAR_V0 asm volatile("s_waitcnt vmcnt(0)\ns_barrier" ::: "memory")
#define BAR_RAW asm volatile("s_barrier" ::: "memory")

// ---------------------------------------------------------------------------
// cast 4x 1M-elem f32 weight matrices to bf16, packed at dst + which*1M
// ---------------------------------------------------------------------------
__global__ __launch_bounds__(256) void cast_weights(const float* __restrict__ wq,
                                                    const float* __restrict__ wk,
                                                    const float* __restrict__ wv,
                                                    const float* __restrict__ wo,
                                                    unsigned short* __restrict__ dst) {
  int i = blockIdx.x * 256 + threadIdx.x;  // 0..524287, 8 elems each
  int which = i >> 17;
  int off = (i & 131071) * 8;
  const float* src = which == 0 ? wq : which == 1 ? wk : which == 2 ? wv : wo;
  load8cv(src + off, dst + (size_t)which * 1048576 + off);
}

// ---------------------------------------------------------------------------
// C[M][N] = A[M][K] @ Bt[N][K]^T, epilogue (acc+bias)*oscale. 128x64 tile,
// BK=64, 4 waves (2x2), wave = 64x32. B (bf16) staged via global_load_lds;
// A staged via gload_lds if bf16 else reg-convert. Linear LDS (m97-style).
// ---------------------------------------------------------------------------
template <typename TA, typename TOUT>
__global__ __launch_bounds__(256) void gemm_bias(const TA* __restrict__ A,
                                                 const unsigned short* __restrict__ Bt,
                                                 const float* __restrict__ bias,
                                                 TOUT* __restrict__ C,
                                                 int M, int N, int K, float oscale) {
  __shared__ __align__(16) char lds[24576];  // As 16KB | Bs 8KB
  char* As = lds;
  char* Bs = lds + 16384;
  const int tid = threadIdx.x;
  const int lane = tid & 63;
  const int wv = tid >> 6;
  const int g = lane >> 4, r = lane & 15;
  const int wm = wv >> 1, wn = wv & 1;
  const int m0 = blockIdx.y * 128, n0 = blockIdx.x * 64;

  f32x4 acc[4][2];
#pragma unroll
  for (int m = 0; m < 4; ++m)
#pragma unroll
    for (int n = 0; n < 2; ++n) acc[m][n] = (f32x4){0.f, 0.f, 0.f, 0.f};

  for (int k0 = 0; k0 < K; k0 += 64) {
    __syncthreads();
    // B tile 64x64 bf16 = 8KB: 2 gload_lds per wave
#pragma unroll
    for (int i = 0; i < 2; ++i) {
      int c = (wv * 2 + i) * 64 + lane;  // 0..511
      int row = c >> 3;
      gl2lds16(Bt + (size_t)(n0 + row) * K + k0 + (c & 7) * 8, Bs + (wv * 2 + i) * 1024);
    }
    // A tile 128x64 = 16KB
    if constexpr (sizeof(TA) == 2) {
#pragma unroll
      for (int i = 0; i < 4; ++i) {
        int c = (wv * 4 + i) * 64 + lane;  // 0..1023
        int row = c >> 3;
        gl2lds16(A + (size_t)(m0 + row) * K + k0 + (c & 7) * 8, As + (wv * 4 + i) * 1024);
      }
    } else {
#pragma unroll
      for (int i = 0; i < 4; ++i) {
        int c = tid + i * 256;
        int row = c >> 3, e = (c & 7) * 8;
        load8cv(A + (size_t)(m0 + row) * K + k0 + e, As + c * 16);
      }
    }
    __syncthreads();  // full drain (single-buffered, m97 structure)
#pragma unroll
    for (int kk = 0; kk < 2; ++kk) {
      short8 af[4], bq[2];
#pragma unroll
      for (int m = 0; m < 4; ++m)
        af[m] = *(const short8*)(As + (wm * 64 + m * 16 + r) * 128 + kk * 64 + g * 16);
#pragma unroll
      for (int n = 0; n < 2; ++n)
        bq[n] = *(const short8*)(Bs + (wn * 32 + n * 16 + r) * 128 + kk * 64 + g * 16);
#pragma unroll
      for (int m = 0; m < 4; ++m)
#pragma unroll
        for (int n = 0; n < 2; ++n) acc[m][n] = MFMA16(af[m], bq[n], acc[m][n]);
    }
  }

#pragma unroll
  for (int n = 0; n < 2; ++n) {
    int col = n0 + wn * 32 + n * 16 + r;
    float bv = bias[col];
#pragma unroll
    for (int m = 0; m < 4; ++m) {
#pragma unroll
      for (int i = 0; i < 4; ++i) {
        int rowg = m0 + wm * 64 + m * 16 + 4 * g + i;
        storec(C + (size_t)rowg * N + col, (acc[m][n][i] + bv) * oscale);
      }
    }
  }
}

// ---------------------------------------------------------------------------
// V16[b*2048+s][h*64+d] -> Vt[(b*16+h)*64+d][s]  (bf16)
// ---------------------------------------------------------------------------
__global__ __launch_bounds__(256) void transpose_v(const unsigned short* __restrict__ V,
                                                   unsigned short* __restrict__ Vt) {
  int t = blockIdx.x * 256 + threadIdx.x;
  int d = t & 63;
  int sc = (t >> 6) & 255;
  int bh = t >> 14;
  int b = bh >> 4, h = bh & 15;
  unsigned short vals[8];
#pragma unroll
  for (int j = 0; j < 8; ++j)
    vals[j] = V[(size_t)(b * 2048 + sc * 8 + j) * 1024 + h * 64 + d];
  *(short8*)&Vt[((size_t)bh * 64 + d) * 2048 + sc * 8] = *(short8*)vals;
}

// ---------------------------------------------------------------------------
// Fused attention, T3/T4-lite pipeline. 4 waves x 16 q-rows; Q pre-scaled.
// LDS: 2x16KB K/V double-buffer + 4x2KB bf16 pbuf = 40KB -> 4 blocks/CU.
// Staging: global_load_lds w/ pre-swizzled per-lane SOURCE (rule 21), linear
// LDS dest, XOR-swizzled reads (byte ^ (row&7)<<4). Per tile: issue next
// tile's 4 loads, s_waitcnt vmcnt(4), s_barrier, compute, s_barrier.
// Prefetch never drained (counted vmcnt, not 0).
// ---------------------------------------------------------------------------
__global__ __launch_bounds__(256, 4) void attn_fused(const unsigned short* __restrict__ Q,
                                                     const unsigned short* __restrict__ K,
                                                     const unsigned short* __restrict__ Vt,
                                                     float* __restrict__ attn,
                                                     unsigned short* __restrict__ O) {
  __shared__ __align__(16) char lds[40960];  // buf0 16KB | buf1 16KB | pbuf 4x2KB
  const int tid = threadIdx.x;
  const int lane = tid & 63;
  const int wv = tid >> 6;
  const int g = lane >> 4, r = lane & 15;
  // XCD-chunked bijective swizzle (1024 = 8*128)
  int nb = (blockIdx.x & 7) * 128 + (blockIdx.x >> 3);
  const int qt = nb & 31, bh = nb >> 5, h = bh & 15, b = bh >> 4;
  const int qloc = qt * 64 + wv * 16;
  const int qrow0 = b * 2048 + qloc;
  const unsigned short* Kbh = K + (size_t)b * 2048 * 1024 + h * 64;
  const unsigned short* Vbh = Vt + (size_t)bh * 64 * 2048;
  float* attn_bh = attn + (size_t)bh * 2048 * 2048;
  char* pb = lds + 32768 + wv * 2048;

  short8 qf[2];
#pragma unroll
  for (int kk = 0; kk < 2; ++kk)
    qf[kk] = *(const short8*)&Q[(size_t)(qrow0 + r) * 1024 + h * 64 + kk * 32 + g * 8];

  // ---- staging issue helpers (4 gload_lds per wave per tile) ----
  // pass 1: K tile 128 rows x 128B into 16KB buf
#define P1_ISSUE(bb, ktt)                                                      \
  do {                                                                         \
    _Pragma("unroll") for (int i_ = 0; i_ < 4; ++i_) {                         \
      int c_ = (wv * 4 + i_) * 64 + lane;                                      \
      int kr_ = c_ >> 3;                                                       \
      int scb_ = ((c_ & 7) * 16) ^ ((kr_ & 7) << 4);                           \
      gl2lds16(Kbh + (size_t)((ktt) + kr_) * 1024 + (scb_ >> 1),               \
               (bb) + (wv * 4 + i_) * 1024);                                   \
    }                                                                          \
  } while (0)
  // pass 2: K 64 rows (chunks 0..511) + V 64 rows (512..1023)
#define P2_ISSUE(bb, ktt)                                                      \
  do {                                                                         \
    _Pragma("unroll") for (int i_ = 0; i_ < 4; ++i_) {                         \
      int c_ = (wv * 4 + i_) * 64 + lane;                                      \
      int kr_ = (c_ >> 3) & 63;                                                \
      int scb_ = ((c_ & 7) * 16) ^ ((kr_ & 7) << 4);                           \
      const unsigned short* src_ =                                             \
          (c_ < 512) ? (Kbh + (size_t)((ktt) + kr_) * 1024 + (scb_ >> 1))      \
                     : (Vbh + (size_t)kr_ * 2048 + (ktt) + (scb_ >> 1));       \
      gl2lds16(src_, (bb) + (wv * 4 + i_) * 1024);                             \
    }                                                                          \
  } while (0)

  // ---------------- pass 1: row sums of exp, KVBLK=128 ----------------
  float lrow[4] = {0.f, 0.f, 0.f, 0.f};
  int cur = 0;
  P1_ISSUE(lds, 0);
  for (int t = 0; t < 16; ++t) {
    char* bcur = lds + (cur << 14);
    char* bnxt = lds + ((cur ^ 1) << 14);
    if (t < 15) {
      P1_ISSUE(bnxt, (t + 1) * 128);
      BAR_V4;
    } else {
      BAR_V0;
    }
#pragma unroll
    for (int ct = 0; ct < 8; ++ct) {
      int row = ct * 16 + r;
      int sw = (row & 7) << 4;
      f32x4 s = (f32x4){0.f, 0.f, 0.f, 0.f};
      s = MFMA16(qf[0], *(const short8*)(bcur + ((row * 128 + g * 16) ^ sw)), s);
      s = MFMA16(qf[1], *(const short8*)(bcur + ((row * 128 + 64 + g * 16) ^ sw)), s);
#pragma unroll
      for (int i = 0; i < 4; ++i) lrow[i] += __expf(s[i]);
    }
    BAR_RAW;  // all waves done reading bcur before it is re-staged
    cur ^= 1;
  }
  float linv[4];
#pragma unroll
  for (int i = 0; i < 4; ++i) {
    float l = lrow[i];
    l += __shfl_xor(l, 1);
    l += __shfl_xor(l, 2);
    l += __shfl_xor(l, 4);
    l += __shfl_xor(l, 8);
    linv[i] = 1.0f / l;
  }

  // ---------------- pass 2: P store + PV, KVBLK=64 ----------------
  f32x4 oacc[4];
#pragma unroll
  for (int i = 0; i < 4; ++i) oacc[i] = (f32x4){0.f, 0.f, 0.f, 0.f};

  cur = 0;
  P2_ISSUE(lds, 0);
  for (int t = 0; t < 32; ++t) {
    char* bcur = lds + (cur << 14);
    char* bnxt = lds + ((cur ^ 1) << 14);
    int kt = t * 64;
    if (t < 31) {
      P2_ISSUE(bnxt, kt + 64);
      BAR_V4;
    } else {
      BAR_V0;
    }
    // QK^T
    f32x4 s[4];
#pragma unroll
    for (int ct = 0; ct < 4; ++ct) {
      int row = ct * 16 + r;
      int sw = (row & 7) << 4;
      s[ct] = (f32x4){0.f, 0.f, 0.f, 0.f};
      s[ct] = MFMA16(qf[0], *(const short8*)(bcur + ((row * 128 + g * 16) ^ sw)), s[ct]);
      s[ct] = MFMA16(qf[1], *(const short8*)(bcur + ((row * 128 + 64 + g * 16) ^ sw)), s[ct]);
    }
    // normalized P -> per-wave bf16 pbuf [16][128B], swizzled
#pragma unroll
    for (int ct = 0; ct < 4; ++ct) {
#pragma unroll
      for (int i = 0; i < 4; ++i) {
        float p = __expf(s[ct][i]) * linv[i];
        int pr = 4 * g + i;
        *(unsigned short*)(pb + ((pr * 128 + (ct * 16 + r) * 2) ^ ((pr & 7) << 4))) = f2bf(p);
      }
    }
    // coalesced attention store: 4 reps x (4 rows x 256B f32)
#pragma unroll
    for (int rep = 0; rep < 4; ++rep) {
      int row = rep * 4 + g;
      const unsigned short* ps =
          (const unsigned short*)(pb + ((row * 128 + r * 8) ^ ((row & 7) << 4)));
      f32x4 o4;
      o4[0] = bf2f(ps[0]); o4[1] = bf2f(ps[1]);
      o4[2] = bf2f(ps[2]); o4[3] = bf2f(ps[3]);
      *(f32x4*)&attn_bh[(size_t)(qloc + row) * 2048 + kt + r * 4] = o4;
    }
    // PV: O[16x64] += P[16x64] @ V[64x64]
#pragma unroll
    for (int kk2 = 0; kk2 < 2; ++kk2) {
      short8 pa = *(const short8*)(pb + ((r * 128 + kk2 * 64 + g * 16) ^ ((r & 7) << 4)));
#pragma unroll
      for (int ct2 = 0; ct2 < 4; ++ct2) {
        int vrow = ct2 * 16 + r;
        short8 vf = *(const short8*)(bcur + 8192 +
                                     ((vrow * 128 + kk2 * 64 + g * 16) ^ ((vrow & 7) << 4)));
        oacc[ct2] = MFMA16(pa, vf, oacc[ct2]);
      }
    }
    BAR_RAW;
    cur ^= 1;
  }
#pragma unroll
  for (int ct2 = 0; ct2 < 4; ++ct2)
#pragma unroll
    for (int i = 0; i < 4; ++i)
      O[(size_t)(qrow0 + 4 * g + i) * 1024 + h * 64 + ct2 * 16 + r] = f2bf(oacc[ct2][i]);
#undef P1_ISSUE
#undef P2_ISSUE
}

// ---------------------------------------------------------------------------
extern "C" void kernel_launch(void* const* d_in, const int* in_sizes, int n_in,
                              void* d_out, int out_size, void* d_ws, size_t ws_size,
                              hipStream_t stream) {
  const float* q_in = (const float*)d_in[0];
  const float* k_in = (const float*)d_in[1];
  const float* v_in = (const float*)d_in[2];
  const float* wq = (const float*)d_in[3];
  const float* bq = (const float*)d_in[4];
  const float* wk = (const float*)d_in[5];
  const float* bk = (const float*)d_in[6];
  const float* wv = (const float*)d_in[7];
  const float* bv = (const float*)d_in[8];
  const float* wo = (const float*)d_in[9];
  const float* bo = (const float*)d_in[10];

  char* ws = (char*)d_ws;
  const size_t MB8 = 8ull * 1024 * 1024;
  unsigned short* W16 = (unsigned short*)(ws);            // 4 x 2MB bf16 weights
  unsigned short* Q16 = (unsigned short*)(ws + MB8);
  unsigned short* K16 = (unsigned short*)(ws + 2 * MB8);
  unsigned short* V16 = (unsigned short*)(ws + 3 * MB8);
  unsigned short* Vt  = (unsigned short*)(ws + 4 * MB8);
  unsigned short* O16 = (unsigned short*)(ws + 3 * MB8);  // alias V16 (dead after transpose)

  float* out = (float*)d_out;
  float* attn = out + 4194304ull;

  dim3 blk(256);
  dim3 gproj(16, 32);  // N/64 x M/128
  cast_weights<<<dim3(2048), blk, 0, stream>>>(wq, wk, wv, wo, W16);
  gemm_bias<float, unsigned short><<<gproj, blk, 0, stream>>>(q_in, W16, bq, Q16, 4096, 1024, 1024, 0.125f);
  gemm_bias<float, unsigned short><<<gproj, blk, 0, stream>>>(k_in, W16 + 1048576, bk, K16, 4096, 1024, 1024, 1.0f);
  gemm_bias<float, unsigned short><<<gproj, blk, 0, stream>>>(v_in, W16 + 2097152, bv, V16, 4096, 1024, 1024, 1.0f);
  transpose_v<<<dim3(2048), blk, 0, stream>>>(V16, Vt);
  attn_fused<<<dim3(1024), blk, 0, stream>>>(Q16, K16, Vt, attn, O16);
  gemm_bias<unsigned short, float><<<gproj, blk, 0, stream>>>(O16, W16 + 3145728, bo, out, 4096, 1024, 1024, 1.0f);
}